// Round 4
// baseline (94.232 us; speedup 1.0000x reference)
//
#include <hip/hip_runtime.h>
#include <math.h>

#define NB 37
#define BB 4
#define CC 2
#define FF 1025
#define TT 2048
#define EE 128
#define DD 260
#define EPSF 1e-5f
#define CHS 9           // max K chunks of 32 (Kpad<=288)

typedef short s16x8 __attribute__((ext_vector_type(8)));
typedef float f32x4 __attribute__((ext_vector_type(4)));

__device__ __forceinline__ unsigned short f2bf(float f) {
    unsigned u = __builtin_bit_cast(unsigned, f);
    unsigned r = (u + 0x7FFFu + ((u >> 16) & 1u)) >> 16;
    return (unsigned short)r;
}

// ---------------------------------------------------------------------------
// Kernel 1: per-band prep (unchanged from round 3).
// A[e,k] = gamma[d(k)] * g[e]*v[e,d(k)]/||v[e]||, ATg layout [n][ch][e][32k],
// zero-padded within partial chunks. s1[e]=sum A, s2p[e]=sum beta*W + bias.
// ---------------------------------------------------------------------------
__global__ __launch_bounds__(256) void prep_kernel(
    const float* __restrict__ gamma, const float* __restrict__ beta,
    const float* __restrict__ v, const float* __restrict__ g,
    const float* __restrict__ bias, const int* __restrict__ bwidth,
    unsigned short* __restrict__ ATg, float* __restrict__ s1o, float* __restrict__ s2o)
{
    int bid = blockIdx.x;
    int n   = bid >> 4;
    int eg  = bid & 15;
    int tid = threadIdx.x;
    int el  = tid >> 5;          // 0..7
    int kk  = tid & 31;
    int e   = eg * 8 + el;

    int bw    = bwidth[n];
    int Deff  = 4 * bw;
    int twobw = 2 * bw;
    int nCh   = (Deff + 31) >> 5;

    const float* vp = v + (size_t)(n * EE + e) * DD;

    float sq = 0.f;
    for (int d = kk; d < DD; d += 32) { float val = vp[d]; sq = fmaf(val, val, sq); }
    #pragma unroll
    for (int m = 16; m >= 1; m >>= 1) sq += __shfl_xor(sq, m);

    float rv = g[n * EE + e] * rsqrtf(sq);

    float s1 = 0.f, s2 = 0.f;
    unsigned short* Abase = ATg + (size_t)n * CHS * (EE * 32) + e * 32 + kk;
    for (int ch = 0; ch < nCh; ++ch) {
        int k = ch * 32 + kk;
        float a = 0.f;
        if (k < Deff) {
            int d = (k >= twobw) ? (130 + k - twobw) : k;
            float W = rv * vp[d];
            a = gamma[n * DD + d] * W;
            s1 += a;
            s2 = fmaf(beta[n * DD + d], W, s2);
        }
        Abase[(size_t)ch * (EE * 32)] = f2bf(a);
    }
    #pragma unroll
    for (int m = 16; m >= 1; m >>= 1) { s1 += __shfl_xor(s1, m); s2 += __shfl_xor(s2, m); }
    if (kk == 0) {
        s1o[n * EE + e] = s1;
        s2o[n * EE + e] = s2 + bias[n * EE + e];
    }
}

// ---------------------------------------------------------------------------
// Kernel 2: fully wave-independent fused stats + MFMA GEMM.
// Block = 128t x 128e (4 waves of 64t x 64e). No LDS staging: MFMA fragments
// for X and A are loaded straight from global (fragment shape == load shape).
// Per-lane stats reduced via shfl_xor over lane bits 4/5 (the k-groups).
// ---------------------------------------------------------------------------
template <bool PRED>
__device__ __forceinline__ void do_chunk(
    const float* __restrict__ xt, const unsigned* offP,
    const s16x8* __restrict__ Ab, int ch, int nPairs, int ksub,
    f32x4 (&acc)[4][4], float (&sA)[4], float (&qA)[4])
{
    s16x8 bfr[4];
    #pragma unroll
    for (int ni = 0; ni < 4; ++ni) bfr[ni] = Ab[ch * 512 + ni * 64];

    int pb = ch * 16 + (ksub << 2);
    unsigned o[4]; bool val[4];
    #pragma unroll
    for (int j = 0; j < 4; ++j) {
        int p = pb + j;
        val[j] = !PRED || (p < nPairs);
        o[j] = offP[p];
    }

    #pragma unroll
    for (int mi = 0; mi < 4; ++mi) {
        float2 vv[4];
        #pragma unroll
        for (int j = 0; j < 4; ++j) {
            vv[j] = make_float2(0.f, 0.f);
            if (val[j])
                vv[j] = *reinterpret_cast<const float2*>(xt + o[j] + mi * 32);
        }
        float s = sA[mi], q = qA[mi];
        #pragma unroll
        for (int j = 0; j < 4; ++j) {
            s += vv[j].x + vv[j].y;
            q = fmaf(vv[j].x, vv[j].x, q);
            q = fmaf(vv[j].y, vv[j].y, q);
        }
        sA[mi] = s; qA[mi] = q;
        s16x8 af;
        #pragma unroll
        for (int j = 0; j < 4; ++j) {
            af[2 * j]     = (short)f2bf(vv[j].x);
            af[2 * j + 1] = (short)f2bf(vv[j].y);
        }
        #pragma unroll
        for (int ni = 0; ni < 4; ++ni)
            acc[mi][ni] = __builtin_amdgcn_mfma_f32_16x16x32_bf16(
                af, bfr[ni], acc[mi][ni], 0, 0, 0);
    }
}

__global__ __launch_bounds__(256) void fused_kernel(
    const float* __restrict__ x, const int* __restrict__ bstart,
    const int* __restrict__ bwidth,
    const unsigned short* __restrict__ ATg, const float* __restrict__ s1a,
    const float* __restrict__ s2a, float* __restrict__ out)
{
    int bid = blockIdx.x;
    int tt  = bid & 15;                 // T/128 = 16
    int n   = (bid >> 4) % NB;
    int b   = bid / (16 * NB);
    int t0  = tt * 128;
    int f0  = bstart[n];
    int bw  = bwidth[n];
    int nPairs = 2 * bw;
    int Deff   = 4 * bw;

    int tid  = threadIdx.x;
    int lane = tid & 63;
    int l15  = lane & 15;
    int ksub = lane >> 4;

    __shared__ unsigned offP[CHS * 16];

    if (tid < CHS * 16) {
        unsigned off = 0;
        if (tid < nPairs) {
            int c = (tid >= bw) ? 1 : 0;
            int w = tid - c * bw;
            off = (unsigned)(((b * CC + c) * FF + f0 + w) * (TT * 2));
        }
        offP[tid] = off;
    }
    __syncthreads();

    int wv    = tid >> 6;
    int twave = t0 + (wv >> 1) * 64;    // absolute t base for this wave
    int ewave = (wv & 1) * 64;

    f32x4 acc[4][4];
    #pragma unroll
    for (int mi = 0; mi < 4; ++mi)
        #pragma unroll
        for (int ni = 0; ni < 4; ++ni)
            acc[mi][ni] = (f32x4){0.f, 0.f, 0.f, 0.f};
    float sA[4] = {0.f, 0.f, 0.f, 0.f};
    float qA[4] = {0.f, 0.f, 0.f, 0.f};

    const float* xt = x + (size_t)(twave + l15) * 2;
    const s16x8* Ab = reinterpret_cast<const s16x8*>(
        ATg + (size_t)n * CHS * (EE * 32) + ((ewave + l15) * 32 + ksub * 8));

    int nChF = Deff >> 5;               // full chunks (all bands >= 2)
    int rem  = Deff & 31;               // only band 36 (bw=65)

    for (int ch = 0; ch < nChF; ++ch)
        do_chunk<false>(xt, offP, Ab, ch, nPairs, ksub, acc, sA, qA);
    if (rem)
        do_chunk<true>(xt, offP, Ab, nChF, nPairs, ksub, acc, sA, qA);

    // ---- stats finalize: reduce over k-groups (lane bits 4,5), broadcast
    float inv = 1.f / (float)Deff;
    float mrow[4][4], rrow[4][4];
    #pragma unroll
    for (int mi = 0; mi < 4; ++mi) {
        float s = sA[mi], q = qA[mi];
        s += __shfl_xor(s, 16); s += __shfl_xor(s, 32);
        q += __shfl_xor(q, 16); q += __shfl_xor(q, 32);
        float mean = s * inv;
        float var  = fmaf(q, inv, -mean * mean);
        float rs   = rsqrtf(var + EPSF);
        #pragma unroll
        for (int j = 0; j < 4; ++j) {
            int src = (ksub << 2) + j;      // lane holding row ksub*4+j
            mrow[mi][j] = __shfl(mean, src);
            rrow[mi][j] = __shfl(rs, src);
        }
    }

    // ---- epilogue: z = rs*(acc - mean*s1) + s2
    float s1r[4], s2r[4];
    #pragma unroll
    for (int ni = 0; ni < 4; ++ni) {
        int e = ewave + ni * 16 + l15;
        s1r[ni] = s1a[n * EE + e];
        s2r[ni] = s2a[n * EE + e];
    }
    size_t outRow = ((size_t)(b * NB + n)) * TT;
    #pragma unroll
    for (int mi = 0; mi < 4; ++mi) {
        #pragma unroll
        for (int j = 0; j < 4; ++j) {
            int t = twave + mi * 16 + (ksub << 2) + j;
            float m = mrow[mi][j], r = rrow[mi][j];
            float* op = out + (outRow + t) * EE + ewave + l15;
            #pragma unroll
            for (int ni = 0; ni < 4; ++ni)
                op[ni * 16] = fmaf(r, acc[mi][ni][j] - m * s1r[ni], s2r[ni]);
        }
    }
}

// ---------------------------------------------------------------------------
extern "C" void kernel_launch(void* const* d_in, const int* in_sizes, int n_in,
                              void* d_out, int out_size, void* d_ws, size_t ws_size,
                              hipStream_t stream)
{
    const float* x      = (const float*)d_in[0];
    const float* gamma  = (const float*)d_in[1];
    const float* beta   = (const float*)d_in[2];
    const float* v      = (const float*)d_in[3];
    const float* g      = (const float*)d_in[4];
    const float* bias   = (const float*)d_in[5];
    const int*   bstart = (const int*)d_in[6];
    const int*   bwidth = (const int*)d_in[7];
    float* out = (float*)d_out;

    unsigned short* ATg = (unsigned short*)d_ws;                 // 37*9*128*32 bf16
    float* s1  = (float*)(ATg + (size_t)NB * CHS * EE * 32);     // 37*128 f32
    float* s2p = s1 + NB * EE;                                   // 37*128 f32

    prep_kernel<<<NB * 16, 256, 0, stream>>>(gamma, beta, v, g, bias, bwidth, ATg, s1, s2p);
    fused_kernel<<<BB * NB * 16, 256, 0, stream>>>(x, bstart, bwidth, ATg, s1, s2p, out);
}